// Round 1
// baseline (4606.646 us; speedup 1.0000x reference)
//
#include <hip/hip_runtime.h>
#include <hip/hip_bf16.h>
#include <math.h>

// ---------------------------------------------------------------------------
// Problem constants (from reference): D=256, LVL=17, MIX=20
//   N nodes = 2^18 - 1 = 262143; internal nodes = 2^17 - 1 = 131071
// Key structural facts exploited:
//  * Encoder reads ORIGINAL Feature -> only Feature_New[0] (root) is ever
//    consumed by the decoder. Encoder == one double LSTM cell at node 0.
//  * Decoder level l (size 2^l) reads Feat of its nodes (written by level
//    l-1, except root) and writes children features. Level-order ping-pong.
//  * X_P is written but never read -> dead code.
//  * Output: scalar Loss/17 (float32).
// ---------------------------------------------------------------------------

#define LOG2PI 1.8378770664093453f

__device__ inline float sigm(float x) { return 1.0f / (1.0f + expf(-x)); }

// ---------------------------------------------------------------------------
// Generic fp32 tiled GEMM:  C[M,N] = act( sum_p A_p[M,K_p] @ W_p[N,K_p]^T + b )
// Up to 3 (A,W,K) pairs (K=0 -> unused). NT layout: dot along contiguous K.
// BM=BN=64, BK=32, 256 threads, 4x4 per-thread microtile.
// ---------------------------------------------------------------------------
template <int ACT>
__global__ __launch_bounds__(256) void gemm_nt(
    const float* __restrict__ A0, int lda0, const float* __restrict__ W0, int ldw0, int K0,
    const float* __restrict__ A1, int lda1, const float* __restrict__ W1, int ldw1, int K1,
    const float* __restrict__ A2, int lda2, const float* __restrict__ W2, int ldw2, int K2,
    const float* __restrict__ bias0, const float* __restrict__ bias1,
    float* __restrict__ C, int ldc, int M, int N)
{
    __shared__ float As[32][68];  // +4 pad: store conflicts ~2-4 way, reads clean
    __shared__ float Ws[32][68];
    const int tid = threadIdx.x;
    const int tx = tid & 15, ty = tid >> 4;
    const int m0 = blockIdx.x * 64, n0 = blockIdx.y * 64;

    float acc[4][4] = {};

    const float* Ap[3] = {A0, A1, A2};
    const float* Wp[3] = {W0, W1, W2};
    const int la_[3] = {lda0, lda1, lda2};
    const int lw_[3] = {ldw0, ldw1, ldw2};
    const int Kp[3] = {K0, K1, K2};

    for (int p = 0; p < 3; ++p) {
        const int K = Kp[p];
        if (K == 0) continue;
        const float* __restrict__ A = Ap[p];
        const float* __restrict__ W = Wp[p];
        const int la = la_[p], lw = lw_[p];
        for (int k0 = 0; k0 < K; k0 += 32) {
            __syncthreads();
            {
                int i = tid;
                #pragma unroll
                for (int it = 0; it < 2; ++it, i += 256) {
                    int r = i >> 3, c4 = (i & 7) << 2;
                    int gm = m0 + r, gk = k0 + c4;
                    float4 v = {0.f, 0.f, 0.f, 0.f};
                    if (gm < M && gk < K)  // K % 4 == 0 always here
                        v = *(const float4*)(A + (size_t)gm * la + gk);
                    As[c4 + 0][r] = v.x; As[c4 + 1][r] = v.y;
                    As[c4 + 2][r] = v.z; As[c4 + 3][r] = v.w;
                }
                i = tid;
                #pragma unroll
                for (int it = 0; it < 2; ++it, i += 256) {
                    int r = i >> 3, c4 = (i & 7) << 2;
                    int gn = n0 + r, gk = k0 + c4;
                    float4 v = {0.f, 0.f, 0.f, 0.f};
                    if (gn < N && gk < K)
                        v = *(const float4*)(W + (size_t)gn * lw + gk);
                    Ws[c4 + 0][r] = v.x; Ws[c4 + 1][r] = v.y;
                    Ws[c4 + 2][r] = v.z; Ws[c4 + 3][r] = v.w;
                }
            }
            __syncthreads();
            #pragma unroll
            for (int k = 0; k < 32; ++k) {
                float4 a = *(const float4*)&As[k][ty << 2];
                float4 b = *(const float4*)&Ws[k][tx << 2];
                acc[0][0] += a.x * b.x; acc[0][1] += a.x * b.y; acc[0][2] += a.x * b.z; acc[0][3] += a.x * b.w;
                acc[1][0] += a.y * b.x; acc[1][1] += a.y * b.y; acc[1][2] += a.y * b.z; acc[1][3] += a.y * b.w;
                acc[2][0] += a.z * b.x; acc[2][1] += a.z * b.y; acc[2][2] += a.z * b.z; acc[2][3] += a.z * b.w;
                acc[3][0] += a.w * b.x; acc[3][1] += a.w * b.y; acc[3][2] += a.w * b.z; acc[3][3] += a.w * b.w;
            }
        }
    }

    #pragma unroll
    for (int i = 0; i < 4; ++i) {
        int m = m0 + (ty << 2) + i;
        if (m >= M) continue;
        #pragma unroll
        for (int jj = 0; jj < 4; ++jj) {
            int n = n0 + (tx << 2) + jj;
            if (n >= N) continue;
            float v = acc[i][jj] + bias0[n] + (bias1 ? bias1[n] : 0.f);
            if (ACT == 1) v = tanhf(v);
            C[(size_t)m * ldc + n] = v;
        }
    }
}

// ---------------------------------------------------------------------------
// Encoder: only the root's feature matters. One block.
//   gates[g] = Wih_e[g,:8].X[ch] + bih[g] + Whh_e[g,:128].h_ch + bhh[g]
// ---------------------------------------------------------------------------
__global__ __launch_bounds__(256) void encoder_root(
    const float* __restrict__ X, const float* __restrict__ Feature,
    const float* __restrict__ Wih, const float* __restrict__ Whh,
    const float* __restrict__ bih, const float* __restrict__ bhh,
    float* __restrict__ Fcur0)
{
    __shared__ float gsh[2][512];
    __shared__ float hc[2][256];
    const int t = threadIdx.x;
    for (int ch = 0; ch < 2; ++ch) {
        const int node = 1 + ch;
        const float* x = X + node * 8;
        const float* h = Feature + (size_t)node * 256;  // h = cols 0..127
        #pragma unroll
        for (int gi = 0; gi < 2; ++gi) {
            int g = t + gi * 256;
            float s = bih[g] + bhh[g];
            const float* wi = Wih + (size_t)g * 8;
            #pragma unroll
            for (int k = 0; k < 8; ++k) s += wi[k] * x[k];
            const float* wh = Whh + (size_t)g * 128;
            for (int k = 0; k < 128; ++k) s += wh[k] * h[k];
            gsh[ch][g] = s;
        }
    }
    __syncthreads();
    {
        int ch = t >> 7, u = t & 127;
        float i_ = gsh[ch][u], f_ = gsh[ch][128 + u];
        float gg = gsh[ch][256 + u], o_ = gsh[ch][384 + u];
        float c = Feature[(size_t)(1 + ch) * 256 + 128 + u];
        float c2 = sigm(f_) * c + sigm(i_) * tanhf(gg);
        float hv = sigm(o_) * tanhf(c2);
        hc[ch][u] = hv;
        hc[ch][128 + u] = c2;
    }
    __syncthreads();
    Fcur0[t] = hc[0][t] + hc[1][t];
}

// ---------------------------------------------------------------------------
// Decoder elementwise LSTM: G (B,1024) gates, Z (B,512) [h_f|c_f] -> H, C (B,256)
// ---------------------------------------------------------------------------
__global__ __launch_bounds__(256) void lstm_ew(
    const float* __restrict__ G, const float* __restrict__ Z,
    float* __restrict__ H, float* __restrict__ C, int total)
{
    int idx = blockIdx.x * 256 + threadIdx.x;
    if (idx >= total) return;
    int j = idx >> 8, t = idx & 255;
    const float* g = G + (size_t)j * 1024;
    float i_ = g[t], f_ = g[256 + t], gg = g[512 + t], o_ = g[768 + t];
    float cf = Z[(size_t)j * 512 + 256 + t];
    float c2 = sigm(f_) * cf + sigm(i_) * tanhf(gg);
    float hv = sigm(o_) * tanhf(c2);
    H[idx] = hv;
    C[idx] = c2;
}

// ---------------------------------------------------------------------------
// NLL + swap + child-feature write. One 64-lane wave per node; lanes 0..31
// handle prm_l, lanes 32..63 prm_r; lane k<20 = mixture component k.
// ---------------------------------------------------------------------------
__device__ inline float halfmax(float v) {
    #pragma unroll
    for (int o = 16; o >= 1; o >>= 1) v = fmaxf(v, __shfl_xor(v, o));
    return v;
}
__device__ inline float halfsum(float v) {
    #pragma unroll
    for (int o = 16; o >= 1; o >>= 1) v += __shfl_xor(v, o);
    return v;
}
__device__ inline float lse20(float t) {
    float m = halfmax(t);
    float s = halfsum(expf(t - m));  // exp(-inf - m) = 0 for k>=20 lanes
    return m + logf(s);
}

__global__ __launch_bounds__(256) void nll_kernel(
    const float* __restrict__ Y, const float* __restrict__ X,
    const float* __restrict__ H, const float* __restrict__ Cb,
    float* __restrict__ FeatNext, float* __restrict__ loss,
    int Bc, long long nb, int j0, float scale, int writeFeat)
{
    __shared__ float lsum[4];
    const int wid = threadIdx.x >> 6;
    const int lane = threadIdx.x & 63;
    const int j = blockIdx.x * 4 + wid;
    float chosen = 0.f;
    if (j < Bc) {
        const int half = lane >> 5, k = lane & 31;
        const float* yb = Y + (size_t)(2 * j + half) * 264;
        float v = (k < 20) ? yb[k] : -INFINITY;
        float mm = halfmax(v);
        float se = halfsum((k < 20) ? expf(v - mm) : 0.f);
        float lpi = v - mm - logf(se);
        float mx = 0, my = 0, sx = 1, sy = 1, rho = 0, omr = 1, cxy = 0;
        float ma = 0, mb2 = 0, sa = 1, sb = 1, rab = 0, omr2 = 1, cab = 0;
        float ms = 0, ss2 = 1, csl = 0;
        if (k < 20) {
            mx = yb[20 + k]; my = yb[40 + k];
            float lsx = yb[60 + k], lsy = yb[80 + k];
            sx = expf(lsx); sy = expf(lsy);
            rho = tanhf(yb[100 + k]); omr = 1.f - rho * rho;
            cxy = LOG2PI + lsx + lsy + 0.5f * logf(omr);
            ma = yb[120 + k]; mb2 = yb[140 + k];
            float lsa = yb[160 + k], lsb = yb[180 + k];
            sa = expf(lsa); sb = expf(lsb);
            rab = tanhf(yb[200 + k]); omr2 = 1.f - rab * rab;
            cab = LOG2PI + lsa + lsb + 0.5f * logf(omr2);
            ms = yb[220 + k]; float lss = yb[240 + k];
            ss2 = expf(lss);
            csl = 0.5f * LOG2PI + lss;
        }
        float lq0, lq1, lq2;
        {
            float q0 = yb[260], q1 = yb[261], q2 = yb[262];
            float qm = fmaxf(q0, fmaxf(q1, q2));
            float l = logf(expf(q0 - qm) + expf(q1 - qm) + expf(q2 - qm)) + qm;
            lq0 = q0 - l; lq1 = q1 - l; lq2 = q2 - l;
        }
        const long long fi = nb + j0 + j;
        const float* pl = X + (size_t)(2 * fi + 1) * 8;
        const float* pr = X + (size_t)(2 * fi + 2) * 8;
        float res[2];
        #pragma unroll
        for (int s = 0; s < 2; ++s) {
            const float* pt = s ? pr : pl;
            float dx = pt[0], dy = pt[1], da = pt[2], db = pt[3], ds = pt[4];
            float t1 = -INFINITY, t2 = -INFINITY, t3 = -INFINITY;
            if (k < 20) {
                float zx = (dx - mx) / sx, zy = (dy - my) / sy;
                float Zz = zx * zx + zy * zy - 2.f * rho * zx * zy;
                t1 = lpi - Zz / (2.f * omr) - cxy;
                float za = (da - ma) / sa, zb = (db - mb2) / sb;
                float Z2 = za * za + zb * zb - 2.f * rab * za * zb;
                t2 = lpi - Z2 / (2.f * omr2) - cab;
                float zs = ds - ms;
                t3 = lpi - (zs * zs) / (2.f * ss2 * ss2) - csl;
            }
            float l1 = lse20(t1), l2 = lse20(t2), l3 = lse20(t3);
            float pen = -(pt[5] * lq0 + pt[6] * lq1 + pt[7] * lq2);
            res[s] = -(l1 + l2 + l3) + pen;
        }
        // half0: res[0]=nll(pl,prml)[direct], res[1]=nll(pr,prml)[swapped]
        // half1: res[0]=nll(pl,prmr)[swapped], res[1]=nll(pr,prmr)[direct]
        float Aval = half ? res[1] : res[0];
        float Bval = half ? res[0] : res[1];
        float direct = Aval + __shfl_xor(Aval, 32);
        float swapped = Bval + __shfl_xor(Bval, 32);
        bool sw = swapped < direct;
        chosen = sw ? swapped : direct;
        if (writeFeat) {
            const size_t Jg = 2 * (size_t)(j0 + j);
            const float* Hj = H + (size_t)j * 256;
            const float* Cj = Cb + (size_t)j * 256;
            const int offL = sw ? 128 : 0;
            const int offR = 128 - offL;
            const int part = lane >> 5;           // 0 -> h half, 1 -> c half
            const int c = (lane & 31) * 4;
            float4 vL = *(const float4*)((part ? Cj : Hj) + offL + c);
            float4 vR = *(const float4*)((part ? Cj : Hj) + offR + c);
            *(float4*)(FeatNext + Jg * 256 + part * 128 + c) = vL;
            *(float4*)(FeatNext + (Jg + 1) * 256 + part * 128 + c) = vR;
        }
    }
    if (lane == 0) lsum[wid] = chosen;
    __syncthreads();
    if (threadIdx.x == 0) {
        atomicAdd(loss, (lsum[0] + lsum[1] + lsum[2] + lsum[3]) * scale);
    }
}

// ---------------------------------------------------------------------------
extern "C" void kernel_launch(void* const* d_in, const int* in_sizes, int n_in,
                              void* d_out, int out_size, void* d_ws, size_t ws_size,
                              hipStream_t stream)
{
    const float* X       = (const float*)d_in[0];
    const float* Feature = (const float*)d_in[1];
    // d_in[2] = I_flat (indices are arithmetic: li=2fi+1, ri=2fi+2) - unused
    const float* W_ih_e  = (const float*)d_in[3];
    const float* W_hh_e  = (const float*)d_in[4];
    const float* b_ih_e  = (const float*)d_in[5];
    const float* b_hh_e  = (const float*)d_in[6];
    const float* fc_h_W  = (const float*)d_in[7];
    const float* fc_h_b  = (const float*)d_in[8];
    const float* W_ih_d  = (const float*)d_in[9];
    const float* W_hh_d  = (const float*)d_in[10];
    const float* b_ih_d  = (const float*)d_in[11];
    const float* b_hh_d  = (const float*)d_in[12];
    const float* fc_W    = (const float*)d_in[13];
    const float* fc_b    = (const float*)d_in[14];
    float* out = (float*)d_out;
    float* ws  = (float*)d_ws;

    hipMemsetAsync(d_out, 0, sizeof(float), stream);

    // ws layout (floats):
    //   featA: 65536*256 (cur at even levels; written as next at odd levels)
    //   featB: 32768*256 (cur at odd levels; max written at l=14)
    //   scratch: Z (CB*512) | G (CB*1024) | H (CB*256) | C (CB*256) | Y (CB*528)
    const size_t featFloats = (size_t)65536 * 256 + (size_t)32768 * 256;
    int CB = 16384;
    while (CB > 2048 &&
           (featFloats + (size_t)CB * 2576) * sizeof(float) > ws_size)
        CB >>= 1;

    float* featA = ws;
    float* featB = ws + (size_t)65536 * 256;
    float* Zb = featB + (size_t)32768 * 256;
    float* Gb = Zb + (size_t)CB * 512;
    float* Hb = Gb + (size_t)CB * 1024;
    float* Cc = Hb + (size_t)CB * 256;
    float* Yb = Cc + (size_t)CB * 256;

    encoder_root<<<1, 256, 0, stream>>>(X, Feature, W_ih_e, W_hh_e, b_ih_e, b_hh_e, featA);

    for (int l = 0; l < 17; ++l) {
        const int B = 1 << l;
        const long long nb = B - 1;
        float* Fcur  = (l & 1) ? featB : featA;
        float* Fnext = (l & 1) ? featA : featB;
        const int writeFeat = (l < 16) ? 1 : 0;
        const float scale = 1.f / ((float)B * 17.f);
        for (int j0 = 0; j0 < B; j0 += CB) {
            const int Bc = (B - j0 < CB) ? (B - j0) : CB;
            // Z = tanh(Fcur @ fc_h_W^T + fc_h_b)  (Bc x 512)
            dim3 g1((Bc + 63) / 64, 8);
            gemm_nt<1><<<g1, 256, 0, stream>>>(
                Fcur + (size_t)j0 * 256, 256, fc_h_W, 256, 256,
                nullptr, 0, nullptr, 0, 0,
                nullptr, 0, nullptr, 0, 0,
                fc_h_b, nullptr, Zb, 512, Bc, 512);
            // G = [X_f | f_f] @ W_ih_d^T + h_f @ W_hh_d^T + b_ih_d + b_hh_d
            dim3 g2((Bc + 63) / 64, 16);
            gemm_nt<0><<<g2, 256, 0, stream>>>(
                X + (size_t)(nb + j0) * 8, 8, W_ih_d, 264, 8,
                Fcur + (size_t)j0 * 256, 256, W_ih_d + 8, 264, 256,
                Zb, 512, W_hh_d, 256, 256,
                b_ih_d, b_hh_d, Gb, 1024, Bc, 1024);
            // h_o, c_o
            int tot = Bc * 256;
            lstm_ew<<<(tot + 255) / 256, 256, 0, stream>>>(Gb, Zb, Hb, Cc, tot);
            // Y = Hlr(2Bc,128) @ fc_W^T + fc_b  (2Bc x 263, ld 264)
            dim3 g3((2 * Bc + 63) / 64, 5);
            gemm_nt<0><<<g3, 256, 0, stream>>>(
                Hb, 128, fc_W, 128, 128,
                nullptr, 0, nullptr, 0, 0,
                nullptr, 0, nullptr, 0, 0,
                fc_b, nullptr, Yb, 264, 2 * Bc, 263);
            // NLL + swap + children
            nll_kernel<<<(Bc + 3) / 4, 256, 0, stream>>>(
                Yb, X, Hb, Cc,
                writeFeat ? Fnext : nullptr, out,
                Bc, nb, j0, scale, writeFeat);
        }
    }
}

// Round 2
// 2117.549 us; speedup vs baseline: 2.1755x; 2.1755x over previous
//
#include <hip/hip_runtime.h>
#include <hip/hip_bf16.h>
#include <math.h>

// ---------------------------------------------------------------------------
// D=256, LVL=17, MIX=20. N nodes = 2^18-1; internal = 2^17-1 = 131071.
// Structure exploited:
//  * Encoder reads ORIGINAL Feature -> only root's encoded feature survives.
//  * Decoder is 17 sequential levels; level l has B=2^l nodes.
//  * X_P dead. Output = scalar Loss/17.
// R2: all GEMMs in bf16 MFMA (16x16x32), activations/features stored bf16,
//     fp32 accumulate + fp32 NLL math.
// ---------------------------------------------------------------------------

#define LOG2PI 1.8378770664093453f

typedef __attribute__((ext_vector_type(8))) short short8;
typedef __attribute__((ext_vector_type(4))) float f32x4;

__device__ inline float sigm(float x) { return 1.0f / (1.0f + expf(-x)); }

__device__ inline ushort f2b(float v) {
    union { float f; unsigned u; } x; x.f = v;
    unsigned r = x.u + 0x7fffu + ((x.u >> 16) & 1u);
    return (ushort)(r >> 16);
}
__device__ inline float b2f(ushort h) {
    union { unsigned u; float f; } x; x.u = ((unsigned)h) << 16; return x.f;
}

__device__ inline void gload16(const void* g, void* l) {
    __builtin_amdgcn_global_load_lds(
        (const __attribute__((address_space(1))) unsigned*)g,
        (__attribute__((address_space(3))) unsigned*)l, 16, 0, 0);
}

// ---------------------------------------------------------------------------
// bf16 NT GEMM: C[M,N] = act(A[M,K] @ B[N,K]^T + bias0 (+bias1))
// 128x128 tile, BK=64, 256 threads (4 waves 2x2), 16x16x32 MFMA, 4x4 frags.
// LDS XOR-swizzled (slot ^= row&7) via pre-swizzled global_load_lds source.
// K multiple of 64. Staging rows clamped (pads must be handled by caller).
// OUT_MODE 0: fp32 C, 1: bf16 C.
// ---------------------------------------------------------------------------
template <int ACT, int OUT_MODE>
__global__ __launch_bounds__(256) void gemm_bf16(
    const ushort* __restrict__ A, int lda, int Mclamp,
    const ushort* __restrict__ B, int ldb, int Nclamp,
    const float* __restrict__ bias0, const float* __restrict__ bias1,
    float* __restrict__ Cf, ushort* __restrict__ Cb, int ldc,
    int M, int N, int K)
{
    __shared__ ushort As[128 * 64];
    __shared__ ushort Bs[128 * 64];
    const int tid = threadIdx.x;
    const int lane = tid & 63;
    const int w = tid >> 6;
    const int wr = w >> 1, wc = w & 1;
    const int fr = lane & 15, fq = lane >> 4;
    const int m0 = blockIdx.x * 128, n0 = blockIdx.y * 128;

    f32x4 acc[4][4] = {};

    for (int k0 = 0; k0 < K; k0 += 64) {
        __syncthreads();
        #pragma unroll
        for (int it = 0; it < 4; ++it) {
            const int i = it * 256 + tid;
            const int row = i >> 3, slot = i & 7;
            const int sl = slot ^ (row & 7);
            const int wbase = (i - lane) * 8;  // ushort index of wave-uniform base
            {
                int gm = m0 + row; gm = gm <= Mclamp ? gm : Mclamp;
                gload16(A + (size_t)gm * lda + k0 + sl * 8, &As[wbase]);
            }
            {
                int gn = n0 + row; gn = gn <= Nclamp ? gn : Nclamp;
                gload16(B + (size_t)gn * ldb + k0 + sl * 8, &Bs[wbase]);
            }
        }
        __syncthreads();
        #pragma unroll
        for (int ks = 0; ks < 2; ++ks) {
            short8 af[4], bfr[4];
            #pragma unroll
            for (int mr = 0; mr < 4; ++mr) {
                const int row = wr * 64 + mr * 16 + fr;
                const int sl = (ks * 4 + fq) ^ (row & 7);
                af[mr] = *(const short8*)&As[row * 64 + sl * 8];
            }
            #pragma unroll
            for (int nc = 0; nc < 4; ++nc) {
                const int row = wc * 64 + nc * 16 + fr;
                const int sl = (ks * 4 + fq) ^ (row & 7);
                bfr[nc] = *(const short8*)&Bs[row * 64 + sl * 8];
            }
            #pragma unroll
            for (int mr = 0; mr < 4; ++mr)
                #pragma unroll
                for (int nc = 0; nc < 4; ++nc)
                    acc[mr][nc] = __builtin_amdgcn_mfma_f32_16x16x32_bf16(
                        af[mr], bfr[nc], acc[mr][nc], 0, 0, 0);
        }
    }

    #pragma unroll
    for (int mr = 0; mr < 4; ++mr) {
        #pragma unroll
        for (int j = 0; j < 4; ++j) {
            const int row = m0 + wr * 64 + mr * 16 + fq * 4 + j;
            if (row >= M) continue;
            #pragma unroll
            for (int nc = 0; nc < 4; ++nc) {
                const int col = n0 + wc * 64 + nc * 16 + fr;
                if (col >= N) continue;
                float v = acc[mr][nc][j] + bias0[col] + (bias1 ? bias1[col] : 0.f);
                if (ACT == 1) v = tanhf(v);
                if (OUT_MODE == 0) Cf[(size_t)row * ldc + col] = v;
                else               Cb[(size_t)row * ldc + col] = f2b(v);
            }
        }
    }
}

// ---------------------------------------------------------------------------
// Weight repack (fp32 -> bf16), once per launch.
// ---------------------------------------------------------------------------
__global__ __launch_bounds__(256) void conv_f2b(const float* __restrict__ s,
                                                ushort* __restrict__ d, int n)
{
    int i = blockIdx.x * 256 + threadIdx.x;
    if (i < n) d[i] = f2b(s[i]);
}
// Wg[1024][576] = [W_ih_d (264) | W_hh_d (256) | zeros (56)]
__global__ __launch_bounds__(256) void pack_wg(const float* __restrict__ Wih,
                                               const float* __restrict__ Whh,
                                               ushort* __restrict__ d)
{
    int i = blockIdx.x * 256 + threadIdx.x;
    if (i >= 1024 * 576) return;
    int n = i / 576, c = i % 576;
    float v = 0.f;
    if (c < 264) v = Wih[n * 264 + c];
    else if (c < 520) v = Whh[n * 256 + (c - 264)];
    d[i] = f2b(v);
}
// Wy[264][128]: rows 0..262 = fc_W, row 263 zeros
__global__ __launch_bounds__(256) void pack_wy(const float* __restrict__ W,
                                               ushort* __restrict__ d)
{
    int i = blockIdx.x * 256 + threadIdx.x;
    if (i >= 264 * 128) return;
    int r = i / 128;
    d[i] = f2b(r < 263 ? W[i] : 0.f);
}

// ---------------------------------------------------------------------------
// Per-chunk A-pack for gates GEMM: Ap[j][576] = [X (8) | f_f (256) | h_f (256) | 0]
// One block of 576 threads per node j.
// ---------------------------------------------------------------------------
__global__ __launch_bounds__(576) void pack_A(
    const float* __restrict__ Xf, const ushort* __restrict__ Fcur,
    const ushort* __restrict__ Zb, ushort* __restrict__ Ap)
{
    const int j = blockIdx.x, c = threadIdx.x;
    ushort v;
    if (c < 8)        v = f2b(Xf[j * 8 + c]);
    else if (c < 264) v = Fcur[(size_t)j * 256 + (c - 8)];
    else if (c < 520) v = Zb[(size_t)j * 512 + (c - 264)];
    else              v = 0;
    Ap[(size_t)j * 576 + c] = v;
}

// ---------------------------------------------------------------------------
// Encoder: only the root feature matters. One block.
// ---------------------------------------------------------------------------
__global__ __launch_bounds__(256) void encoder_root(
    const float* __restrict__ X, const float* __restrict__ Feature,
    const float* __restrict__ Wih, const float* __restrict__ Whh,
    const float* __restrict__ bih, const float* __restrict__ bhh,
    ushort* __restrict__ Fcur0)
{
    __shared__ float gsh[2][512];
    __shared__ float hc[2][256];
    const int t = threadIdx.x;
    for (int ch = 0; ch < 2; ++ch) {
        const int node = 1 + ch;
        const float* x = X + node * 8;
        const float* h = Feature + (size_t)node * 256;
        #pragma unroll
        for (int gi = 0; gi < 2; ++gi) {
            int g = t + gi * 256;
            float s = bih[g] + bhh[g];
            const float* wi = Wih + (size_t)g * 8;
            #pragma unroll
            for (int k = 0; k < 8; ++k) s += wi[k] * x[k];
            const float* wh = Whh + (size_t)g * 128;
            for (int k = 0; k < 128; ++k) s += wh[k] * h[k];
            gsh[ch][g] = s;
        }
    }
    __syncthreads();
    {
        int ch = t >> 7, u = t & 127;
        float i_ = gsh[ch][u], f_ = gsh[ch][128 + u];
        float gg = gsh[ch][256 + u], o_ = gsh[ch][384 + u];
        float c = Feature[(size_t)(1 + ch) * 256 + 128 + u];
        float c2 = sigm(f_) * c + sigm(i_) * tanhf(gg);
        hc[ch][u] = sigm(o_) * tanhf(c2);
        hc[ch][128 + u] = c2;
    }
    __syncthreads();
    Fcur0[t] = f2b(hc[0][t] + hc[1][t]);
}

// ---------------------------------------------------------------------------
// Decoder elementwise LSTM: G fp32 (B,1024), Z bf16 (B,512) -> H,C bf16 (B,256)
// ---------------------------------------------------------------------------
__global__ __launch_bounds__(256) void lstm_ew(
    const float* __restrict__ G, const ushort* __restrict__ Z,
    ushort* __restrict__ H, ushort* __restrict__ C, int total)
{
    int idx = blockIdx.x * 256 + threadIdx.x;
    if (idx >= total) return;
    int j = idx >> 8, t = idx & 255;
    const float* g = G + (size_t)j * 1024;
    float i_ = g[t], f_ = g[256 + t], gg = g[512 + t], o_ = g[768 + t];
    float cf = b2f(Z[(size_t)j * 512 + 256 + t]);
    float c2 = sigm(f_) * cf + sigm(i_) * tanhf(gg);
    H[idx] = f2b(sigm(o_) * tanhf(c2));
    C[idx] = f2b(c2);
}

// ---------------------------------------------------------------------------
// NLL + swap + child-feature write. One wave per node.
// ---------------------------------------------------------------------------
__device__ inline float halfmax(float v) {
    #pragma unroll
    for (int o = 16; o >= 1; o >>= 1) v = fmaxf(v, __shfl_xor(v, o));
    return v;
}
__device__ inline float halfsum(float v) {
    #pragma unroll
    for (int o = 16; o >= 1; o >>= 1) v += __shfl_xor(v, o);
    return v;
}
__device__ inline float lse20(float t) {
    float m = halfmax(t);
    float s = halfsum(expf(t - m));
    return m + logf(s);
}

__global__ __launch_bounds__(256) void nll_kernel(
    const float* __restrict__ Y, const float* __restrict__ X,
    const ushort* __restrict__ H, const ushort* __restrict__ Cb,
    ushort* __restrict__ FeatNext, float* __restrict__ loss,
    int Bc, long long nb, int j0, float scale, int writeFeat)
{
    __shared__ float lsum[4];
    const int wid = threadIdx.x >> 6;
    const int lane = threadIdx.x & 63;
    const int j = blockIdx.x * 4 + wid;
    float chosen = 0.f;
    if (j < Bc) {
        const int half = lane >> 5, k = lane & 31;
        const float* yb = Y + (size_t)(2 * j + half) * 264;
        float v = (k < 20) ? yb[k] : -INFINITY;
        float mm = halfmax(v);
        float se = halfsum((k < 20) ? expf(v - mm) : 0.f);
        float lpi = v - mm - logf(se);
        float mx = 0, my = 0, sx = 1, sy = 1, rho = 0, omr = 1, cxy = 0;
        float ma = 0, mb2 = 0, sa = 1, sb = 1, rab = 0, omr2 = 1, cab = 0;
        float ms = 0, ss2 = 1, csl = 0;
        if (k < 20) {
            mx = yb[20 + k]; my = yb[40 + k];
            float lsx = yb[60 + k], lsy = yb[80 + k];
            sx = expf(lsx); sy = expf(lsy);
            rho = tanhf(yb[100 + k]); omr = 1.f - rho * rho;
            cxy = LOG2PI + lsx + lsy + 0.5f * logf(omr);
            ma = yb[120 + k]; mb2 = yb[140 + k];
            float lsa = yb[160 + k], lsb = yb[180 + k];
            sa = expf(lsa); sb = expf(lsb);
            rab = tanhf(yb[200 + k]); omr2 = 1.f - rab * rab;
            cab = LOG2PI + lsa + lsb + 0.5f * logf(omr2);
            ms = yb[220 + k]; float lss = yb[240 + k];
            ss2 = expf(lss);
            csl = 0.5f * LOG2PI + lss;
        }
        float lq0, lq1, lq2;
        {
            float q0 = yb[260], q1 = yb[261], q2 = yb[262];
            float qm = fmaxf(q0, fmaxf(q1, q2));
            float l = logf(expf(q0 - qm) + expf(q1 - qm) + expf(q2 - qm)) + qm;
            lq0 = q0 - l; lq1 = q1 - l; lq2 = q2 - l;
        }
        const long long fi = nb + j0 + j;
        const float* pl = X + (size_t)(2 * fi + 1) * 8;
        const float* pr = X + (size_t)(2 * fi + 2) * 8;
        float res[2];
        #pragma unroll
        for (int s = 0; s < 2; ++s) {
            const float* pt = s ? pr : pl;
            float dx = pt[0], dy = pt[1], da = pt[2], db = pt[3], ds = pt[4];
            float t1 = -INFINITY, t2 = -INFINITY, t3 = -INFINITY;
            if (k < 20) {
                float zx = (dx - mx) / sx, zy = (dy - my) / sy;
                float Zz = zx * zx + zy * zy - 2.f * rho * zx * zy;
                t1 = lpi - Zz / (2.f * omr) - cxy;
                float za = (da - ma) / sa, zb = (db - mb2) / sb;
                float Z2 = za * za + zb * zb - 2.f * rab * za * zb;
                t2 = lpi - Z2 / (2.f * omr2) - cab;
                float zs = ds - ms;
                t3 = lpi - (zs * zs) / (2.f * ss2 * ss2) - csl;
            }
            float l1 = lse20(t1), l2 = lse20(t2), l3 = lse20(t3);
            float pen = -(pt[5] * lq0 + pt[6] * lq1 + pt[7] * lq2);
            res[s] = -(l1 + l2 + l3) + pen;
        }
        float Aval = half ? res[1] : res[0];
        float Bval = half ? res[0] : res[1];
        float direct = Aval + __shfl_xor(Aval, 32);
        float swapped = Bval + __shfl_xor(Bval, 32);
        bool sw = swapped < direct;
        chosen = sw ? swapped : direct;
        if (writeFeat) {
            const size_t Jg = 2 * (size_t)(j0 + j);
            const ushort* Hj = H + (size_t)j * 256;
            const ushort* Cj = Cb + (size_t)j * 256;
            const int offL = sw ? 128 : 0;
            const int offR = 128 - offL;
            const int part = lane >> 5;           // 0 -> h half, 1 -> c half
            const int c = (lane & 31) * 4;        // 4 bf16 per lane
            ushort4 vL = *(const ushort4*)((part ? Cj : Hj) + offL + c);
            ushort4 vR = *(const ushort4*)((part ? Cj : Hj) + offR + c);
            *(ushort4*)(FeatNext + Jg * 256 + part * 128 + c) = vL;
            *(ushort4*)(FeatNext + (Jg + 1) * 256 + part * 128 + c) = vR;
        }
    }
    if (lane == 0) lsum[wid] = chosen;
    __syncthreads();
    if (threadIdx.x == 0)
        atomicAdd(loss, (lsum[0] + lsum[1] + lsum[2] + lsum[3]) * scale);
}

// ---------------------------------------------------------------------------
extern "C" void kernel_launch(void* const* d_in, const int* in_sizes, int n_in,
                              void* d_out, int out_size, void* d_ws, size_t ws_size,
                              hipStream_t stream)
{
    const float* X       = (const float*)d_in[0];
    const float* Feature = (const float*)d_in[1];
    const float* W_ih_e  = (const float*)d_in[3];
    const float* W_hh_e  = (const float*)d_in[4];
    const float* b_ih_e  = (const float*)d_in[5];
    const float* b_hh_e  = (const float*)d_in[6];
    const float* fc_h_W  = (const float*)d_in[7];
    const float* fc_h_b  = (const float*)d_in[8];
    const float* W_ih_d  = (const float*)d_in[9];
    const float* W_hh_d  = (const float*)d_in[10];
    const float* b_ih_d  = (const float*)d_in[11];
    const float* b_hh_d  = (const float*)d_in[12];
    const float* fc_W    = (const float*)d_in[13];
    const float* fc_b    = (const float*)d_in[14];
    float* out = (float*)d_out;

    hipMemsetAsync(d_out, 0, sizeof(float), stream);

    // --- workspace carve-up (bytes, 256-aligned) ---
    char* cur = (char*)d_ws;
    auto take = [&](size_t bytes) {
        char* p = cur;
        cur += (bytes + 255) & ~(size_t)255;
        return p;
    };
    // fixed
    ushort* featA = (ushort*)take((size_t)65536 * 256 * 2);
    ushort* featB = (ushort*)take((size_t)32768 * 256 * 2);
    ushort* Wz    = (ushort*)take((size_t)512 * 256 * 2);
    ushort* Wg    = (ushort*)take((size_t)1024 * 576 * 2);
    ushort* Wy    = (ushort*)take((size_t)264 * 128 * 2);
    const size_t fixed_used = (size_t)(cur - (char*)d_ws);
    // per-chunk bytes: Zb 1024 + Ap 1152 + G 4096 + H 512 + C 512 + Y 2112 = 9408
    int CB = 16384;
    while (CB > 2048 && fixed_used + (size_t)CB * 9408 + 4096 > ws_size) CB >>= 1;
    ushort* Zb = (ushort*)take((size_t)CB * 512 * 2);
    ushort* Ap = (ushort*)take((size_t)CB * 576 * 2);
    float*  Gb = (float*) take((size_t)CB * 1024 * 4);
    ushort* Hb = (ushort*)take((size_t)CB * 256 * 2);
    ushort* Cc = (ushort*)take((size_t)CB * 256 * 2);
    float*  Yb = (float*) take((size_t)2 * CB * 264 * 4);

    // --- weight repack (bf16) ---
    conv_f2b<<<(512 * 256 + 255) / 256, 256, 0, stream>>>(fc_h_W, Wz, 512 * 256);
    pack_wg<<<(1024 * 576 + 255) / 256, 256, 0, stream>>>(W_ih_d, W_hh_d, Wg);
    pack_wy<<<(264 * 128 + 255) / 256, 256, 0, stream>>>(fc_W, Wy);

    encoder_root<<<1, 256, 0, stream>>>(X, Feature, W_ih_e, W_hh_e, b_ih_e, b_hh_e, featA);

    for (int l = 0; l < 17; ++l) {
        const int B = 1 << l;
        const long long nb = B - 1;
        ushort* Fcur  = (l & 1) ? featB : featA;
        ushort* Fnext = (l & 1) ? featA : featB;
        const int writeFeat = (l < 16) ? 1 : 0;
        const float scale = 1.f / ((float)B * 17.f);
        for (int j0 = 0; j0 < B; j0 += CB) {
            const int Bc = (B - j0 < CB) ? (B - j0) : CB;
            const int mg = (Bc + 127) / 128;
            // Z = tanh(Fcur @ Wz^T + fc_h_b): [Bc x 512] bf16
            gemm_bf16<1, 1><<<dim3(mg, 4), 256, 0, stream>>>(
                Fcur + (size_t)j0 * 256, 256, Bc - 1,
                Wz, 256, 511,
                fc_h_b, nullptr, nullptr, Zb, 512, Bc, 512, 256);
            // Ap = [X | f_f | h_f | 0]: [Bc x 576] bf16
            pack_A<<<Bc, 576, 0, stream>>>(
                X + (size_t)(nb + j0) * 8, Fcur + (size_t)j0 * 256, Zb, Ap);
            // G = Ap @ Wg^T + b_ih_d + b_hh_d: [Bc x 1024] fp32
            gemm_bf16<0, 0><<<dim3(mg, 8), 256, 0, stream>>>(
                Ap, 576, Bc - 1,
                Wg, 576, 1023,
                b_ih_d, b_hh_d, Gb, nullptr, 1024, Bc, 1024, 576);
            // LSTM elementwise
            lstm_ew<<<(Bc * 256 + 255) / 256, 256, 0, stream>>>(Gb, Zb, Hb, Cc, Bc * 256);
            // Y = H(2Bc,128) @ Wy^T + fc_b: [2Bc x 263] fp32 (ld 264)
            gemm_bf16<0, 0><<<dim3((2 * Bc + 127) / 128, 3), 256, 0, stream>>>(
                Hb, 128, 2 * Bc - 1,
                Wy, 128, 263,
                fc_b, nullptr, Yb, nullptr, 264, 2 * Bc, 263, 128);
            // NLL + swap + children
            nll_kernel<<<(Bc + 3) / 4, 256, 0, stream>>>(
                Yb, X, Hb, Cc,
                writeFeat ? Fnext : nullptr, out,
                Bc, nb, j0, scale, writeFeat);
        }
    }
}

// Round 3
// 1762.345 us; speedup vs baseline: 2.6139x; 1.2016x over previous
//
#include <hip/hip_runtime.h>
#include <hip/hip_bf16.h>
#include <math.h>

// ---------------------------------------------------------------------------
// D=256, LVL=17, MIX=20. N nodes = 2^18-1; internal = 2^17-1 = 131071.
//  * Encoder reads ORIGINAL Feature -> only root's encoded feature survives.
//  * Decoder: 17 sequential levels; level l has B=2^l nodes. X_P dead.
// R3: fused gates GEMM (3-segment A staging, gate-interleaved Wg,
//     in-register LSTM epilogue via 4-lane shfl_xor). No pack_A, no lstm_ew,
//     no fp32 G buffer.
// ---------------------------------------------------------------------------

#define LOG2PI 1.8378770664093453f

typedef __attribute__((ext_vector_type(8))) short short8;
typedef __attribute__((ext_vector_type(4))) float f32x4;

__device__ inline float sigm(float x) { return 1.0f / (1.0f + expf(-x)); }

__device__ inline ushort f2b(float v) {
    union { float f; unsigned u; } x; x.f = v;
    unsigned r = x.u + 0x7fffu + ((x.u >> 16) & 1u);
    return (ushort)(r >> 16);
}
__device__ inline float b2f(ushort h) {
    union { unsigned u; float f; } x; x.u = ((unsigned)h) << 16; return x.f;
}

__device__ inline void gload16(const void* g, void* l) {
    __builtin_amdgcn_global_load_lds(
        (const __attribute__((address_space(1))) unsigned*)g,
        (__attribute__((address_space(3))) unsigned*)l, 16, 0, 0);
}

// ---------------------------------------------------------------------------
// bf16 NT GEMM: C[M,N] = act(A[M,K] @ B[N,K]^T + bias0 (+bias1))
// 128x128 tile, BK=64, 256 threads (4 waves 2x2), 16x16x32 MFMA.
// LDS XOR-swizzled via pre-swizzled global_load_lds source. K % 64 == 0.
// OUT_MODE 0: fp32 C, 1: bf16 C.
// ---------------------------------------------------------------------------
template <int ACT, int OUT_MODE>
__global__ __launch_bounds__(256) void gemm_bf16(
    const ushort* __restrict__ A, int lda, int Mclamp,
    const ushort* __restrict__ B, int ldb, int Nclamp,
    const float* __restrict__ bias0, const float* __restrict__ bias1,
    float* __restrict__ Cf, ushort* __restrict__ Cb, int ldc,
    int M, int N, int K)
{
    __shared__ ushort As[128 * 64];
    __shared__ ushort Bs[128 * 64];
    const int tid = threadIdx.x;
    const int lane = tid & 63;
    const int w = tid >> 6;
    const int wr = w >> 1, wc = w & 1;
    const int fr = lane & 15, fq = lane >> 4;
    const int m0 = blockIdx.x * 128, n0 = blockIdx.y * 128;

    f32x4 acc[4][4] = {};

    for (int k0 = 0; k0 < K; k0 += 64) {
        __syncthreads();
        #pragma unroll
        for (int it = 0; it < 4; ++it) {
            const int i = it * 256 + tid;
            const int row = i >> 3, slot = i & 7;
            const int sl = slot ^ (row & 7);
            const int wbase = (i - lane) * 8;
            {
                int gm = m0 + row; gm = gm <= Mclamp ? gm : Mclamp;
                gload16(A + (size_t)gm * lda + k0 + sl * 8, &As[wbase]);
            }
            {
                int gn = n0 + row; gn = gn <= Nclamp ? gn : Nclamp;
                gload16(B + (size_t)gn * ldb + k0 + sl * 8, &Bs[wbase]);
            }
        }
        __syncthreads();
        #pragma unroll
        for (int ks = 0; ks < 2; ++ks) {
            short8 af[4], bfr[4];
            #pragma unroll
            for (int mr = 0; mr < 4; ++mr) {
                const int row = wr * 64 + mr * 16 + fr;
                const int sl = (ks * 4 + fq) ^ (row & 7);
                af[mr] = *(const short8*)&As[row * 64 + sl * 8];
            }
            #pragma unroll
            for (int nc = 0; nc < 4; ++nc) {
                const int row = wc * 64 + nc * 16 + fr;
                const int sl = (ks * 4 + fq) ^ (row & 7);
                bfr[nc] = *(const short8*)&Bs[row * 64 + sl * 8];
            }
            #pragma unroll
            for (int mr = 0; mr < 4; ++mr)
                #pragma unroll
                for (int nc = 0; nc < 4; ++nc)
                    acc[mr][nc] = __builtin_amdgcn_mfma_f32_16x16x32_bf16(
                        af[mr], bfr[nc], acc[mr][nc], 0, 0, 0);
        }
    }

    #pragma unroll
    for (int mr = 0; mr < 4; ++mr) {
        #pragma unroll
        for (int j = 0; j < 4; ++j) {
            const int row = m0 + wr * 64 + mr * 16 + fq * 4 + j;
            if (row >= M) continue;
            #pragma unroll
            for (int nc = 0; nc < 4; ++nc) {
                const int col = n0 + wc * 64 + nc * 16 + fr;
                if (col >= N) continue;
                float v = acc[mr][nc][j] + bias0[col] + (bias1 ? bias1[col] : 0.f);
                if (ACT == 1) v = tanhf(v);
                if (OUT_MODE == 0) Cf[(size_t)row * ldc + col] = v;
                else               Cb[(size_t)row * ldc + col] = f2b(v);
            }
        }
    }
}

// ---------------------------------------------------------------------------
// Fused gates GEMM + LSTM epilogue.
//   G[j][n'] = [X(8)|F(256)|Zh(256)|pad] @ Wg'[n'][576]^T + bg[n']
//   Wg' gate-interleaved: n' = 4t+g. Epilogue: 4-lane shfl exchange ->
//   each lane owns (node,t): c2 = sigm(f)*c_f + sigm(i)*tanh(g);
//   h = sigm(o)*tanh(c2). Writes H,C bf16 [node][256].
// Grid: ((M+127)/128, 8). K=576.
// ---------------------------------------------------------------------------
__global__ __launch_bounds__(256) void gates_lstm(
    const ushort* __restrict__ Xb,    // row j -> node (nb+j0+j), 8 wide
    const ushort* __restrict__ Fcur,  // [j][256]
    const ushort* __restrict__ Zb,    // [j][512] = [h_f | c_f]
    const ushort* __restrict__ Wg,    // [1024][576] interleaved, cols>=520 zero
    const float*  __restrict__ bg,    // [1024] interleaved b_ih+b_hh
    ushort* __restrict__ H, ushort* __restrict__ C, int M)
{
    __shared__ ushort As[128 * 64];
    __shared__ ushort Bs[128 * 64];
    const int tid = threadIdx.x;
    const int lane = tid & 63;
    const int w = tid >> 6;
    const int wr = w >> 1, wc = w & 1;
    const int fr = lane & 15, fq = lane >> 4;
    const int m0 = blockIdx.x * 128, n0 = blockIdx.y * 128;

    f32x4 acc[4][4] = {};

    for (int k0 = 0; k0 < 576; k0 += 64) {
        __syncthreads();
        const int sbase = k0 >> 3;
        #pragma unroll
        for (int it = 0; it < 4; ++it) {
            const int i = it * 256 + tid;
            const int row = i >> 3, slot = i & 7;
            const int sl = slot ^ (row & 7);
            const int wbase = (i - lane) * 8;
            {
                int gm = m0 + row; gm = gm < M ? gm : M - 1;
                const int a = sbase + sl;
                const ushort* src;
                if (a == 0)      src = Xb   + (size_t)gm * 8;
                else if (a < 33) src = Fcur + (size_t)gm * 256 + (size_t)(a - 1) * 8;
                else if (a < 65) src = Zb   + (size_t)gm * 512 + (size_t)(a - 33) * 8;
                else             src = Zb   + (size_t)gm * 512;   // junk; Wg cols zero
                gload16(src, &As[wbase]);
            }
            gload16(Wg + (size_t)(n0 + row) * 576 + k0 + sl * 8, &Bs[wbase]);
        }
        __syncthreads();
        #pragma unroll
        for (int ks = 0; ks < 2; ++ks) {
            short8 af[4], bfr[4];
            #pragma unroll
            for (int mr = 0; mr < 4; ++mr) {
                const int row = wr * 64 + mr * 16 + fr;
                const int sl = (ks * 4 + fq) ^ (row & 7);
                af[mr] = *(const short8*)&As[row * 64 + sl * 8];
            }
            #pragma unroll
            for (int nc = 0; nc < 4; ++nc) {
                const int row = wc * 64 + nc * 16 + fr;
                const int sl = (ks * 4 + fq) ^ (row & 7);
                bfr[nc] = *(const short8*)&Bs[row * 64 + sl * 8];
            }
            #pragma unroll
            for (int mr = 0; mr < 4; ++mr)
                #pragma unroll
                for (int nc = 0; nc < 4; ++nc)
                    acc[mr][nc] = __builtin_amdgcn_mfma_f32_16x16x32_bf16(
                        af[mr], bfr[nc], acc[mr][nc], 0, 0, 0);
        }
    }

    // ---- LSTM epilogue: lane (fq, fr=4u+q) owns (node = ..fq*4+q, t-idx u) ----
    const int q = fr & 3;
    #pragma unroll
    for (int mr = 0; mr < 4; ++mr) {
        const int node = m0 + wr * 64 + mr * 16 + fq * 4 + q;
        #pragma unroll
        for (int nc = 0; nc < 4; ++nc) {
            const int col = n0 + wc * 64 + nc * 16 + fr;
            f32x4 v = acc[mr][nc];
            const float b = bg[col];
            v[0] += b; v[1] += b; v[2] += b; v[3] += b;
            float gv[4];
            gv[q] = v[q];
            #pragma unroll
            for (int m = 1; m < 4; ++m)
                gv[q ^ m] = __shfl_xor(v[q ^ m], m);
            if (node < M) {
                const int t = (col >> 2) & 255;
                const float cf = b2f(Zb[(size_t)node * 512 + 256 + t]);
                const float c2 = sigm(gv[1]) * cf + sigm(gv[0]) * tanhf(gv[2]);
                const float hv = sigm(gv[3]) * tanhf(c2);
                H[(size_t)node * 256 + t] = f2b(hv);
                C[(size_t)node * 256 + t] = f2b(c2);
            }
        }
    }
}

// ---------------------------------------------------------------------------
// One-time repack kernels.
// ---------------------------------------------------------------------------
__global__ __launch_bounds__(256) void conv_f2b(const float* __restrict__ s,
                                                ushort* __restrict__ d, int n)
{
    int i = blockIdx.x * 256 + threadIdx.x;
    if (i < n) d[i] = f2b(s[i]);
}
// Wg'[n'][576], n'=4t+g, src row n=g*256+t; cols: [W_ih_d(264)|W_hh_d(256)|0]
__global__ __launch_bounds__(256) void pack_wg(const float* __restrict__ Wih,
                                               const float* __restrict__ Whh,
                                               ushort* __restrict__ d)
{
    int i = blockIdx.x * 256 + threadIdx.x;
    if (i >= 1024 * 576) return;
    int np = i / 576, c = i % 576;
    int n = (np & 3) * 256 + (np >> 2);
    float v = 0.f;
    if (c < 264) v = Wih[n * 264 + c];
    else if (c < 520) v = Whh[n * 256 + (c - 264)];
    d[i] = f2b(v);
}
__global__ __launch_bounds__(256) void pack_bg(const float* __restrict__ bih,
                                               const float* __restrict__ bhh,
                                               float* __restrict__ d)
{
    int np = blockIdx.x * 256 + threadIdx.x;
    if (np >= 1024) return;
    int n = (np & 3) * 256 + (np >> 2);
    d[np] = bih[n] + bhh[n];
}
// Wy[264][128]: rows 0..262 = fc_W, row 263 zeros
__global__ __launch_bounds__(256) void pack_wy(const float* __restrict__ W,
                                               ushort* __restrict__ d)
{
    int i = blockIdx.x * 256 + threadIdx.x;
    if (i >= 264 * 128) return;
    int r = i / 128;
    d[i] = f2b(r < 263 ? W[i] : 0.f);
}

// ---------------------------------------------------------------------------
// Encoder: only the root feature matters. One block.
// ---------------------------------------------------------------------------
__global__ __launch_bounds__(256) void encoder_root(
    const float* __restrict__ X, const float* __restrict__ Feature,
    const float* __restrict__ Wih, const float* __restrict__ Whh,
    const float* __restrict__ bih, const float* __restrict__ bhh,
    ushort* __restrict__ Fcur0)
{
    __shared__ float gsh[2][512];
    __shared__ float hc[2][256];
    const int t = threadIdx.x;
    for (int ch = 0; ch < 2; ++ch) {
        const int node = 1 + ch;
        const float* x = X + node * 8;
        const float* h = Feature + (size_t)node * 256;
        #pragma unroll
        for (int gi = 0; gi < 2; ++gi) {
            int g = t + gi * 256;
            float s = bih[g] + bhh[g];
            const float* wi = Wih + (size_t)g * 8;
            #pragma unroll
            for (int k = 0; k < 8; ++k) s += wi[k] * x[k];
            const float* wh = Whh + (size_t)g * 128;
            for (int k = 0; k < 128; ++k) s += wh[k] * h[k];
            gsh[ch][g] = s;
        }
    }
    __syncthreads();
    {
        int ch = t >> 7, u = t & 127;
        float i_ = gsh[ch][u], f_ = gsh[ch][128 + u];
        float gg = gsh[ch][256 + u], o_ = gsh[ch][384 + u];
        float c = Feature[(size_t)(1 + ch) * 256 + 128 + u];
        float c2 = sigm(f_) * c + sigm(i_) * tanhf(gg);
        hc[ch][u] = sigm(o_) * tanhf(c2);
        hc[ch][128 + u] = c2;
    }
    __syncthreads();
    Fcur0[t] = f2b(hc[0][t] + hc[1][t]);
}

// ---------------------------------------------------------------------------
// NLL + swap + child-feature write. One wave per node.
// ---------------------------------------------------------------------------
__device__ inline float halfmax(float v) {
    #pragma unroll
    for (int o = 16; o >= 1; o >>= 1) v = fmaxf(v, __shfl_xor(v, o));
    return v;
}
__device__ inline float halfsum(float v) {
    #pragma unroll
    for (int o = 16; o >= 1; o >>= 1) v += __shfl_xor(v, o);
    return v;
}
__device__ inline float lse20(float t) {
    float m = halfmax(t);
    float s = halfsum(expf(t - m));
    return m + logf(s);
}

__global__ __launch_bounds__(256) void nll_kernel(
    const float* __restrict__ Y, const float* __restrict__ X,
    const ushort* __restrict__ H, const ushort* __restrict__ Cb,
    ushort* __restrict__ FeatNext, float* __restrict__ loss,
    int Bc, long long nb, int j0, float scale, int writeFeat)
{
    __shared__ float lsum[4];
    const int wid = threadIdx.x >> 6;
    const int lane = threadIdx.x & 63;
    const int j = blockIdx.x * 4 + wid;
    float chosen = 0.f;
    if (j < Bc) {
        const int half = lane >> 5, k = lane & 31;
        const float* yb = Y + (size_t)(2 * j + half) * 264;
        float v = (k < 20) ? yb[k] : -INFINITY;
        float mm = halfmax(v);
        float se = halfsum((k < 20) ? expf(v - mm) : 0.f);
        float lpi = v - mm - logf(se);
        float mx = 0, my = 0, sx = 1, sy = 1, rho = 0, omr = 1, cxy = 0;
        float ma = 0, mb2 = 0, sa = 1, sb = 1, rab = 0, omr2 = 1, cab = 0;
        float ms = 0, ss2 = 1, csl = 0;
        if (k < 20) {
            mx = yb[20 + k]; my = yb[40 + k];
            float lsx = yb[60 + k], lsy = yb[80 + k];
            sx = expf(lsx); sy = expf(lsy);
            rho = tanhf(yb[100 + k]); omr = 1.f - rho * rho;
            cxy = LOG2PI + lsx + lsy + 0.5f * logf(omr);
            ma = yb[120 + k]; mb2 = yb[140 + k];
            float lsa = yb[160 + k], lsb = yb[180 + k];
            sa = expf(lsa); sb = expf(lsb);
            rab = tanhf(yb[200 + k]); omr2 = 1.f - rab * rab;
            cab = LOG2PI + lsa + lsb + 0.5f * logf(omr2);
            ms = yb[220 + k]; float lss = yb[240 + k];
            ss2 = expf(lss);
            csl = 0.5f * LOG2PI + lss;
        }
        float lq0, lq1, lq2;
        {
            float q0 = yb[260], q1 = yb[261], q2 = yb[262];
            float qm = fmaxf(q0, fmaxf(q1, q2));
            float l = logf(expf(q0 - qm) + expf(q1 - qm) + expf(q2 - qm)) + qm;
            lq0 = q0 - l; lq1 = q1 - l; lq2 = q2 - l;
        }
        const long long fi = nb + j0 + j;
        const float* pl = X + (size_t)(2 * fi + 1) * 8;
        const float* pr = X + (size_t)(2 * fi + 2) * 8;
        float res[2];
        #pragma unroll
        for (int s = 0; s < 2; ++s) {
            const float* pt = s ? pr : pl;
            float dx = pt[0], dy = pt[1], da = pt[2], db = pt[3], ds = pt[4];
            float t1 = -INFINITY, t2 = -INFINITY, t3 = -INFINITY;
            if (k < 20) {
                float zx = (dx - mx) / sx, zy = (dy - my) / sy;
                float Zz = zx * zx + zy * zy - 2.f * rho * zx * zy;
                t1 = lpi - Zz / (2.f * omr) - cxy;
                float za = (da - ma) / sa, zb = (db - mb2) / sb;
                float Z2 = za * za + zb * zb - 2.f * rab * za * zb;
                t2 = lpi - Z2 / (2.f * omr2) - cab;
                float zs = ds - ms;
                t3 = lpi - (zs * zs) / (2.f * ss2 * ss2) - csl;
            }
            float l1 = lse20(t1), l2 = lse20(t2), l3 = lse20(t3);
            float pen = -(pt[5] * lq0 + pt[6] * lq1 + pt[7] * lq2);
            res[s] = -(l1 + l2 + l3) + pen;
        }
        float Aval = half ? res[1] : res[0];
        float Bval = half ? res[0] : res[1];
        float direct = Aval + __shfl_xor(Aval, 32);
        float swapped = Bval + __shfl_xor(Bval, 32);
        bool sw = swapped < direct;
        chosen = sw ? swapped : direct;
        if (writeFeat) {
            const size_t Jg = 2 * (size_t)(j0 + j);
            const ushort* Hj = H + (size_t)j * 256;
            const ushort* Cj = Cb + (size_t)j * 256;
            const int offL = sw ? 128 : 0;
            const int offR = 128 - offL;
            const int part = lane >> 5;
            const int c = (lane & 31) * 4;
            ushort4 vL = *(const ushort4*)((part ? Cj : Hj) + offL + c);
            ushort4 vR = *(const ushort4*)((part ? Cj : Hj) + offR + c);
            *(ushort4*)(FeatNext + Jg * 256 + part * 128 + c) = vL;
            *(ushort4*)(FeatNext + (Jg + 1) * 256 + part * 128 + c) = vR;
        }
    }
    if (lane == 0) lsum[wid] = chosen;
    __syncthreads();
    if (threadIdx.x == 0)
        atomicAdd(loss, (lsum[0] + lsum[1] + lsum[2] + lsum[3]) * scale);
}

// ---------------------------------------------------------------------------
extern "C" void kernel_launch(void* const* d_in, const int* in_sizes, int n_in,
                              void* d_out, int out_size, void* d_ws, size_t ws_size,
                              hipStream_t stream)
{
    const float* X       = (const float*)d_in[0];
    const float* Feature = (const float*)d_in[1];
    const float* W_ih_e  = (const float*)d_in[3];
    const float* W_hh_e  = (const float*)d_in[4];
    const float* b_ih_e  = (const float*)d_in[5];
    const float* b_hh_e  = (const float*)d_in[6];
    const float* fc_h_W  = (const float*)d_in[7];
    const float* fc_h_b  = (const float*)d_in[8];
    const float* W_ih_d  = (const float*)d_in[9];
    const float* W_hh_d  = (const float*)d_in[10];
    const float* b_ih_d  = (const float*)d_in[11];
    const float* b_hh_d  = (const float*)d_in[12];
    const float* fc_W    = (const float*)d_in[13];
    const float* fc_b    = (const float*)d_in[14];
    const int Nnodes = in_sizes[0] / 8;   // 262143

    float* out = (float*)d_out;
    hipMemsetAsync(d_out, 0, sizeof(float), stream);

    // --- workspace carve-up ---
    char* cur = (char*)d_ws;
    auto take = [&](size_t bytes) {
        char* p = cur;
        cur += (bytes + 255) & ~(size_t)255;
        return p;
    };
    ushort* featA = (ushort*)take((size_t)65536 * 256 * 2);
    ushort* featB = (ushort*)take((size_t)32768 * 256 * 2);
    ushort* Wz    = (ushort*)take((size_t)512 * 256 * 2);
    ushort* Wg    = (ushort*)take((size_t)1024 * 576 * 2);
    ushort* Wy    = (ushort*)take((size_t)264 * 128 * 2);
    float*  bg    = (float*) take((size_t)1024 * 4);
    ushort* Xb    = (ushort*)take((size_t)Nnodes * 8 * 2);
    const size_t fixed_used = (size_t)(cur - (char*)d_ws);
    // per-chunk: Zb 1024 + H 512 + C 512 + Y 2112 = 4160 B/node
    int CB = 16384;
    while (CB > 2048 && fixed_used + (size_t)CB * 4160 + 4096 > ws_size) CB >>= 1;
    ushort* Zb = (ushort*)take((size_t)CB * 512 * 2);
    ushort* Hb = (ushort*)take((size_t)CB * 256 * 2);
    ushort* Cc = (ushort*)take((size_t)CB * 256 * 2);
    float*  Yb = (float*) take((size_t)2 * CB * 264 * 4);

    // --- one-time repack ---
    conv_f2b<<<(512 * 256 + 255) / 256, 256, 0, stream>>>(fc_h_W, Wz, 512 * 256);
    pack_wg<<<(1024 * 576 + 255) / 256, 256, 0, stream>>>(W_ih_d, W_hh_d, Wg);
    pack_bg<<<4, 256, 0, stream>>>(b_ih_d, b_hh_d, bg);
    pack_wy<<<(264 * 128 + 255) / 256, 256, 0, stream>>>(fc_W, Wy);
    conv_f2b<<<(Nnodes * 8 + 255) / 256, 256, 0, stream>>>(X, Xb, Nnodes * 8);

    encoder_root<<<1, 256, 0, stream>>>(X, Feature, W_ih_e, W_hh_e, b_ih_e, b_hh_e, featA);

    for (int l = 0; l < 17; ++l) {
        const int B = 1 << l;
        const long long nb = B - 1;
        ushort* Fcur  = (l & 1) ? featB : featA;
        ushort* Fnext = (l & 1) ? featA : featB;
        const int writeFeat = (l < 16) ? 1 : 0;
        const float scale = 1.f / ((float)B * 17.f);
        for (int j0 = 0; j0 < B; j0 += CB) {
            const int Bc = (B - j0 < CB) ? (B - j0) : CB;
            const int mg = (Bc + 127) / 128;
            // Z = tanh(Fcur @ Wz^T + fc_h_b): [Bc x 512] bf16
            gemm_bf16<1, 1><<<dim3(mg, 4), 256, 0, stream>>>(
                Fcur + (size_t)j0 * 256, 256, Bc - 1,
                Wz, 256, 511,
                fc_h_b, nullptr, nullptr, Zb, 512, Bc, 512, 256);
            // gates + LSTM fused -> H, C bf16
            gates_lstm<<<dim3(mg, 8), 256, 0, stream>>>(
                Xb + (size_t)(nb + j0) * 8,
                Fcur + (size_t)j0 * 256,
                Zb, Wg, bg, Hb, Cc, Bc);
            // Y = H(2Bc,128) @ Wy^T + fc_b: [2Bc x 263] fp32 (ld 264)
            gemm_bf16<0, 0><<<dim3((2 * Bc + 127) / 128, 3), 256, 0, stream>>>(
                Hb, 128, 2 * Bc - 1,
                Wy, 128, 263,
                fc_b, nullptr, Yb, nullptr, 264, 2 * Bc, 263, 128);
            // NLL + swap + children
            nll_kernel<<<(Bc + 3) / 4, 256, 0, stream>>>(
                Yb, X, Hb, Cc,
                writeFeat ? Fnext : nullptr, out,
                Bc, nb, j0, scale, writeFeat);
        }
    }
}

// Round 4
// 1462.864 us; speedup vs baseline: 3.1491x; 1.2047x over previous
//
#include <hip/hip_runtime.h>
#include <hip/hip_bf16.h>
#include <math.h>

// ---------------------------------------------------------------------------
// D=256, LVL=17, MIX=20. N nodes = 2^18-1; internal = 2^17-1 = 131071.
//  * Encoder reads ORIGINAL Feature -> only root's encoded feature survives.
//  * Decoder: 17 sequential levels; level l has B=2^l nodes. X_P dead.
// R4: Y-GEMM fused into NLL (ynll kernel: MFMA Y tile in LDS + wave-per-node
//     NLL). 3 kernels per level. CB=65536 -> single chunk per level.
// ---------------------------------------------------------------------------

#define LOG2PI 1.8378770664093453f

typedef __attribute__((ext_vector_type(8))) short short8;
typedef __attribute__((ext_vector_type(4))) float f32x4;

__device__ inline float sigm(float x) { return 1.0f / (1.0f + expf(-x)); }

__device__ inline ushort f2b(float v) {
    union { float f; unsigned u; } x; x.f = v;
    unsigned r = x.u + 0x7fffu + ((x.u >> 16) & 1u);
    return (ushort)(r >> 16);
}
__device__ inline float b2f(ushort h) {
    union { unsigned u; float f; } x; x.u = ((unsigned)h) << 16; return x.f;
}

__device__ inline void gload16(const void* g, void* l) {
    __builtin_amdgcn_global_load_lds(
        (const __attribute__((address_space(1))) unsigned*)g,
        (__attribute__((address_space(3))) unsigned*)l, 16, 0, 0);
}

// ---------------------------------------------------------------------------
// bf16 NT GEMM (used for Z): C[M,N] = act(A @ B^T + bias0), bf16 out.
// 128x128 tile, BK=64, 4 waves, 16x16x32 MFMA, XOR-swizzled LDS.
// ---------------------------------------------------------------------------
template <int ACT, int OUT_MODE>
__global__ __launch_bounds__(256) void gemm_bf16(
    const ushort* __restrict__ A, int lda, int Mclamp,
    const ushort* __restrict__ B, int ldb, int Nclamp,
    const float* __restrict__ bias0, const float* __restrict__ bias1,
    float* __restrict__ Cf, ushort* __restrict__ Cb, int ldc,
    int M, int N, int K)
{
    __shared__ ushort As[128 * 64];
    __shared__ ushort Bs[128 * 64];
    const int tid = threadIdx.x;
    const int lane = tid & 63;
    const int w = tid >> 6;
    const int wr = w >> 1, wc = w & 1;
    const int fr = lane & 15, fq = lane >> 4;
    const int m0 = blockIdx.x * 128, n0 = blockIdx.y * 128;

    f32x4 acc[4][4] = {};

    for (int k0 = 0; k0 < K; k0 += 64) {
        __syncthreads();
        #pragma unroll
        for (int it = 0; it < 4; ++it) {
            const int i = it * 256 + tid;
            const int row = i >> 3, slot = i & 7;
            const int sl = slot ^ (row & 7);
            const int wbase = (i - lane) * 8;
            {
                int gm = m0 + row; gm = gm <= Mclamp ? gm : Mclamp;
                gload16(A + (size_t)gm * lda + k0 + sl * 8, &As[wbase]);
            }
            {
                int gn = n0 + row; gn = gn <= Nclamp ? gn : Nclamp;
                gload16(B + (size_t)gn * ldb + k0 + sl * 8, &Bs[wbase]);
            }
        }
        __syncthreads();
        #pragma unroll
        for (int ks = 0; ks < 2; ++ks) {
            short8 af[4], bfr[4];
            #pragma unroll
            for (int mr = 0; mr < 4; ++mr) {
                const int row = wr * 64 + mr * 16 + fr;
                const int sl = (ks * 4 + fq) ^ (row & 7);
                af[mr] = *(const short8*)&As[row * 64 + sl * 8];
            }
            #pragma unroll
            for (int nc = 0; nc < 4; ++nc) {
                const int row = wc * 64 + nc * 16 + fr;
                const int sl = (ks * 4 + fq) ^ (row & 7);
                bfr[nc] = *(const short8*)&Bs[row * 64 + sl * 8];
            }
            #pragma unroll
            for (int mr = 0; mr < 4; ++mr)
                #pragma unroll
                for (int nc = 0; nc < 4; ++nc)
                    acc[mr][nc] = __builtin_amdgcn_mfma_f32_16x16x32_bf16(
                        af[mr], bfr[nc], acc[mr][nc], 0, 0, 0);
        }
    }

    #pragma unroll
    for (int mr = 0; mr < 4; ++mr) {
        #pragma unroll
        for (int j = 0; j < 4; ++j) {
            const int row = m0 + wr * 64 + mr * 16 + fq * 4 + j;
            if (row >= M) continue;
            #pragma unroll
            for (int nc = 0; nc < 4; ++nc) {
                const int col = n0 + wc * 64 + nc * 16 + fr;
                if (col >= N) continue;
                float v = acc[mr][nc][j] + bias0[col] + (bias1 ? bias1[col] : 0.f);
                if (ACT == 1) v = tanhf(v);
                if (OUT_MODE == 0) Cf[(size_t)row * ldc + col] = v;
                else               Cb[(size_t)row * ldc + col] = f2b(v);
            }
        }
    }
}

// ---------------------------------------------------------------------------
// Fused gates GEMM + LSTM epilogue (same as R3).
// ---------------------------------------------------------------------------
__global__ __launch_bounds__(256) void gates_lstm(
    const ushort* __restrict__ Xb,
    const ushort* __restrict__ Fcur,
    const ushort* __restrict__ Zb,
    const ushort* __restrict__ Wg,
    const float*  __restrict__ bg,
    ushort* __restrict__ H, ushort* __restrict__ C, int M)
{
    __shared__ ushort As[128 * 64];
    __shared__ ushort Bs[128 * 64];
    const int tid = threadIdx.x;
    const int lane = tid & 63;
    const int w = tid >> 6;
    const int wr = w >> 1, wc = w & 1;
    const int fr = lane & 15, fq = lane >> 4;
    const int m0 = blockIdx.x * 128, n0 = blockIdx.y * 128;

    f32x4 acc[4][4] = {};

    for (int k0 = 0; k0 < 576; k0 += 64) {
        __syncthreads();
        const int sbase = k0 >> 3;
        #pragma unroll
        for (int it = 0; it < 4; ++it) {
            const int i = it * 256 + tid;
            const int row = i >> 3, slot = i & 7;
            const int sl = slot ^ (row & 7);
            const int wbase = (i - lane) * 8;
            {
                int gm = m0 + row; gm = gm < M ? gm : M - 1;
                const int a = sbase + sl;
                const ushort* src;
                if (a == 0)      src = Xb   + (size_t)gm * 8;
                else if (a < 33) src = Fcur + (size_t)gm * 256 + (size_t)(a - 1) * 8;
                else if (a < 65) src = Zb   + (size_t)gm * 512 + (size_t)(a - 33) * 8;
                else             src = Zb   + (size_t)gm * 512;   // junk; Wg cols zero
                gload16(src, &As[wbase]);
            }
            gload16(Wg + (size_t)(n0 + row) * 576 + k0 + sl * 8, &Bs[wbase]);
        }
        __syncthreads();
        #pragma unroll
        for (int ks = 0; ks < 2; ++ks) {
            short8 af[4], bfr[4];
            #pragma unroll
            for (int mr = 0; mr < 4; ++mr) {
                const int row = wr * 64 + mr * 16 + fr;
                const int sl = (ks * 4 + fq) ^ (row & 7);
                af[mr] = *(const short8*)&As[row * 64 + sl * 8];
            }
            #pragma unroll
            for (int nc = 0; nc < 4; ++nc) {
                const int row = wc * 64 + nc * 16 + fr;
                const int sl = (ks * 4 + fq) ^ (row & 7);
                bfr[nc] = *(const short8*)&Bs[row * 64 + sl * 8];
            }
            #pragma unroll
            for (int mr = 0; mr < 4; ++mr)
                #pragma unroll
                for (int nc = 0; nc < 4; ++nc)
                    acc[mr][nc] = __builtin_amdgcn_mfma_f32_16x16x32_bf16(
                        af[mr], bfr[nc], acc[mr][nc], 0, 0, 0);
        }
    }

    const int q = fr & 3;
    #pragma unroll
    for (int mr = 0; mr < 4; ++mr) {
        const int node = m0 + wr * 64 + mr * 16 + fq * 4 + q;
        #pragma unroll
        for (int nc = 0; nc < 4; ++nc) {
            const int col = n0 + wc * 64 + nc * 16 + fr;
            f32x4 v = acc[mr][nc];
            const float b = bg[col];
            v[0] += b; v[1] += b; v[2] += b; v[3] += b;
            float gv[4];
            gv[q] = v[q];
            #pragma unroll
            for (int m = 1; m < 4; ++m)
                gv[q ^ m] = __shfl_xor(v[q ^ m], m);
            if (node < M) {
                const int t = (col >> 2) & 255;
                const float cf = b2f(Zb[(size_t)node * 512 + 256 + t]);
                const float c2 = sigm(gv[1]) * cf + sigm(gv[0]) * tanhf(gv[2]);
                const float hv = sigm(gv[3]) * tanhf(c2);
                H[(size_t)node * 256 + t] = f2b(hv);
                C[(size_t)node * 256 + t] = f2b(c2);
            }
        }
    }
}

// ---------------------------------------------------------------------------
// One-time repack kernels.
// ---------------------------------------------------------------------------
__global__ __launch_bounds__(256) void conv_f2b(const float* __restrict__ s,
                                                ushort* __restrict__ d, int n)
{
    int i = blockIdx.x * 256 + threadIdx.x;
    if (i < n) d[i] = f2b(s[i]);
}
__global__ __launch_bounds__(256) void pack_wg(const float* __restrict__ Wih,
                                               const float* __restrict__ Whh,
                                               ushort* __restrict__ d)
{
    int i = blockIdx.x * 256 + threadIdx.x;
    if (i >= 1024 * 576) return;
    int np = i / 576, c = i % 576;
    int n = (np & 3) * 256 + (np >> 2);
    float v = 0.f;
    if (c < 264) v = Wih[n * 264 + c];
    else if (c < 520) v = Whh[n * 256 + (c - 264)];
    d[i] = f2b(v);
}
__global__ __launch_bounds__(256) void pack_bg(const float* __restrict__ bih,
                                               const float* __restrict__ bhh,
                                               float* __restrict__ d)
{
    int np = blockIdx.x * 256 + threadIdx.x;
    if (np >= 1024) return;
    int n = (np & 3) * 256 + (np >> 2);
    d[np] = bih[n] + bhh[n];
}
// Wy[320][128]: rows 0..262 = fc_W, rows 263..319 zero
__global__ __launch_bounds__(256) void pack_wy(const float* __restrict__ W,
                                               ushort* __restrict__ d)
{
    int i = blockIdx.x * 256 + threadIdx.x;
    if (i >= 320 * 128) return;
    int r = i / 128;
    d[i] = f2b(r < 263 ? W[i] : 0.f);
}

// ---------------------------------------------------------------------------
// Encoder: only the root feature matters. One block.
// ---------------------------------------------------------------------------
__global__ __launch_bounds__(256) void encoder_root(
    const float* __restrict__ X, const float* __restrict__ Feature,
    const float* __restrict__ Wih, const float* __restrict__ Whh,
    const float* __restrict__ bih, const float* __restrict__ bhh,
    ushort* __restrict__ Fcur0)
{
    __shared__ float gsh[2][512];
    __shared__ float hc[2][256];
    const int t = threadIdx.x;
    for (int ch = 0; ch < 2; ++ch) {
        const int node = 1 + ch;
        const float* x = X + node * 8;
        const float* h = Feature + (size_t)node * 256;
        #pragma unroll
        for (int gi = 0; gi < 2; ++gi) {
            int g = t + gi * 256;
            float s = bih[g] + bhh[g];
            const float* wi = Wih + (size_t)g * 8;
            #pragma unroll
            for (int k = 0; k < 8; ++k) s += wi[k] * x[k];
            const float* wh = Whh + (size_t)g * 128;
            for (int k = 0; k < 128; ++k) s += wh[k] * h[k];
            gsh[ch][g] = s;
        }
    }
    __syncthreads();
    {
        int ch = t >> 7, u = t & 127;
        float i_ = gsh[ch][u], f_ = gsh[ch][128 + u];
        float gg = gsh[ch][256 + u], o_ = gsh[ch][384 + u];
        float c = Feature[(size_t)(1 + ch) * 256 + 128 + u];
        float c2 = sigm(f_) * c + sigm(i_) * tanhf(gg);
        hc[ch][u] = sigm(o_) * tanhf(c2);
        hc[ch][128 + u] = c2;
    }
    __syncthreads();
    Fcur0[t] = f2b(hc[0][t] + hc[1][t]);
}

// ---------------------------------------------------------------------------
// Fused Y-GEMM + NLL + swap + child-feature write.
// Block = 16 nodes (256 threads, 4 waves).
//   Phase 1: A = Hb viewed as (2Bc)x128 bf16; stage 32x128 tile in LDS
//            (XOR-swizzled); Y(32x263) = A @ Wy^T + fc_b via MFMA, B-frags
//            straight from global (L2). Y -> LDS fp32 (stride 324).
//   Phase 2: wave w handles nodes w*4..w*4+3: NLL from LDS Y, swap decision,
//            feature write, block loss atomic.
// ---------------------------------------------------------------------------
__device__ inline float halfmax(float v) {
    #pragma unroll
    for (int o = 16; o >= 1; o >>= 1) v = fmaxf(v, __shfl_xor(v, o));
    return v;
}
__device__ inline float halfsum(float v) {
    #pragma unroll
    for (int o = 16; o >= 1; o >>= 1) v += __shfl_xor(v, o);
    return v;
}
__device__ inline float lse20(float t) {
    float m = halfmax(t);
    float s = halfsum(expf(t - m));
    return m + logf(s);
}

__global__ __launch_bounds__(256) void ynll(
    const ushort* __restrict__ Hb, const ushort* __restrict__ Cc,
    const ushort* __restrict__ Wyp,   // [320][128] bf16, rows>=263 zero
    const float* __restrict__ fc_b, const float* __restrict__ X,
    ushort* __restrict__ FeatNext, float* __restrict__ loss,
    int Bc, long long nb, int j0, float scale, int writeFeat)
{
    __shared__ ushort Hs[32 * 128];
    __shared__ float Ys[32][324];
    __shared__ float lsum[4];
    const int tid = threadIdx.x;
    const int lane = tid & 63;
    const int wv = tid >> 6;
    const int fr = lane & 15, fq = lane >> 4;
    const int n16 = blockIdx.x * 16;          // first node of this block

    // ---- stage H tile: rows r = 2*(n16+jj)+half, 128 bf16 each ----
    #pragma unroll
    for (int it = 0; it < 2; ++it) {
        const int i = it * 256 + tid;
        const int row = i >> 4, slot = i & 15;
        const int sl = slot ^ (row & 7);
        int gr = n16 * 2 + row;
        const int grmax = 2 * Bc - 1;
        gr = gr <= grmax ? gr : grmax;
        gload16(Hb + (size_t)gr * 128 + sl * 8, &Hs[(i - lane) * 8]);
    }
    __syncthreads();

    // ---- Y = A @ Wy^T: wave wv owns col-frags wv*5..wv*5+4 (cols wv*80..) ----
    f32x4 acc[2][5] = {};
    #pragma unroll
    for (int ks = 0; ks < 4; ++ks) {
        short8 a[2];
        #pragma unroll
        for (int rf = 0; rf < 2; ++rf) {
            const int row = rf * 16 + fr;
            const int sl = (ks * 4 + fq) ^ (row & 7);
            a[rf] = *(const short8*)&Hs[row * 128 + sl * 8];
        }
        #pragma unroll
        for (int n = 0; n < 5; ++n) {
            const short8 b = *(const short8*)(
                Wyp + (size_t)(wv * 80 + n * 16 + fr) * 128 + ks * 32 + fq * 8);
            acc[0][n] = __builtin_amdgcn_mfma_f32_16x16x32_bf16(a[0], b, acc[0][n], 0, 0, 0);
            acc[1][n] = __builtin_amdgcn_mfma_f32_16x16x32_bf16(a[1], b, acc[1][n], 0, 0, 0);
        }
    }
    #pragma unroll
    for (int rf = 0; rf < 2; ++rf)
        #pragma unroll
        for (int n = 0; n < 5; ++n)
            #pragma unroll
            for (int j = 0; j < 4; ++j) {
                const int row = rf * 16 + fq * 4 + j;
                const int col = wv * 80 + n * 16 + fr;
                Ys[row][col] = acc[rf][n][j] + (col < 263 ? fc_b[col] : 0.f);
            }
    __syncthreads();

    // ---- NLL: wave wv -> nodes jj = wv*4 .. wv*4+3 ----
    float wsum = 0.f;
    const int half = lane >> 5, k = lane & 31;
    #pragma unroll
    for (int s4 = 0; s4 < 4; ++s4) {
        const int jj = wv * 4 + s4;
        const int j = n16 + jj;
        if (j >= Bc) break;
        const float* yb = Ys[2 * jj + half];
        float v = (k < 20) ? yb[k] : -INFINITY;
        float mm = halfmax(v);
        float se = halfsum((k < 20) ? expf(v - mm) : 0.f);
        float lpi = v - mm - logf(se);
        float mx = 0, my = 0, sx = 1, sy = 1, rho = 0, omr = 1, cxy = 0;
        float ma = 0, mb2 = 0, sa = 1, sb = 1, rab = 0, omr2 = 1, cab = 0;
        float ms = 0, ss2 = 1, csl = 0;
        if (k < 20) {
            mx = yb[20 + k]; my = yb[40 + k];
            float lsx = yb[60 + k], lsy = yb[80 + k];
            sx = expf(lsx); sy = expf(lsy);
            rho = tanhf(yb[100 + k]); omr = 1.f - rho * rho;
            cxy = LOG2PI + lsx + lsy + 0.5f * logf(omr);
            ma = yb[120 + k]; mb2 = yb[140 + k];
            float lsa = yb[160 + k], lsb = yb[180 + k];
            sa = expf(lsa); sb = expf(lsb);
            rab = tanhf(yb[200 + k]); omr2 = 1.f - rab * rab;
            cab = LOG2PI + lsa + lsb + 0.5f * logf(omr2);
            ms = yb[220 + k]; float lss = yb[240 + k];
            ss2 = expf(lss);
            csl = 0.5f * LOG2PI + lss;
        }
        float lq0, lq1, lq2;
        {
            float q0 = yb[260], q1 = yb[261], q2 = yb[262];
            float qm = fmaxf(q0, fmaxf(q1, q2));
            float l = logf(expf(q0 - qm) + expf(q1 - qm) + expf(q2 - qm)) + qm;
            lq0 = q0 - l; lq1 = q1 - l; lq2 = q2 - l;
        }
        const long long fi = nb + j0 + j;
        const float* pl = X + (size_t)(2 * fi + 1) * 8;
        const float* pr = X + (size_t)(2 * fi + 2) * 8;
        float res[2];
        #pragma unroll
        for (int s = 0; s < 2; ++s) {
            const float* pt = s ? pr : pl;
            float dx = pt[0], dy = pt[1], da = pt[2], db = pt[3], ds = pt[4];
            float t1 = -INFINITY, t2 = -INFINITY, t3 = -INFINITY;
            if (k < 20) {
                float zx = (dx - mx) / sx, zy = (dy - my) / sy;
                float Zz = zx * zx + zy * zy - 2.f * rho * zx * zy;
                t1 = lpi - Zz / (2.f * omr) - cxy;
                float za = (da - ma) / sa, zb = (db - mb2) / sb;
                float Z2 = za * za + zb * zb - 2.f * rab * za * zb;
                t2 = lpi - Z2 / (2.f * omr2) - cab;
                float zs = ds - ms;
                t3 = lpi - (zs * zs) / (2.f * ss2 * ss2) - csl;
            }
            float l1 = lse20(t1), l2 = lse20(t2), l3 = lse20(t3);
            float pen = -(pt[5] * lq0 + pt[6] * lq1 + pt[7] * lq2);
            res[s] = -(l1 + l2 + l3) + pen;
        }
        float Aval = half ? res[1] : res[0];
        float Bval = half ? res[0] : res[1];
        float direct = Aval + __shfl_xor(Aval, 32);
        float swapped = Bval + __shfl_xor(Bval, 32);
        bool sw = swapped < direct;
        wsum += sw ? swapped : direct;
        if (writeFeat) {
            const size_t Jg = 2 * (size_t)(j0 + j);
            const ushort* Hj = Hb + (size_t)j * 256;
            const ushort* Cj = Cc + (size_t)j * 256;
            const int offL = sw ? 128 : 0;
            const int offR = 128 - offL;
            const int part = lane >> 5;
            const int c = (lane & 31) * 4;
            ushort4 vL = *(const ushort4*)((part ? Cj : Hj) + offL + c);
            ushort4 vR = *(const ushort4*)((part ? Cj : Hj) + offR + c);
            *(ushort4*)(FeatNext + Jg * 256 + part * 128 + c) = vL;
            *(ushort4*)(FeatNext + (Jg + 1) * 256 + part * 128 + c) = vR;
        }
    }
    if (lane == 0) lsum[wv] = wsum;
    __syncthreads();
    if (tid == 0)
        atomicAdd(loss, (lsum[0] + lsum[1] + lsum[2] + lsum[3]) * scale);
}

// ---------------------------------------------------------------------------
extern "C" void kernel_launch(void* const* d_in, const int* in_sizes, int n_in,
                              void* d_out, int out_size, void* d_ws, size_t ws_size,
                              hipStream_t stream)
{
    const float* X       = (const float*)d_in[0];
    const float* Feature = (const float*)d_in[1];
    const float* W_ih_e  = (const float*)d_in[3];
    const float* W_hh_e  = (const float*)d_in[4];
    const float* b_ih_e  = (const float*)d_in[5];
    const float* b_hh_e  = (const float*)d_in[6];
    const float* fc_h_W  = (const float*)d_in[7];
    const float* fc_h_b  = (const float*)d_in[8];
    const float* W_ih_d  = (const float*)d_in[9];
    const float* W_hh_d  = (const float*)d_in[10];
    const float* b_ih_d  = (const float*)d_in[11];
    const float* b_hh_d  = (const float*)d_in[12];
    const float* fc_W    = (const float*)d_in[13];
    const float* fc_b    = (const float*)d_in[14];
    const int Nnodes = in_sizes[0] / 8;   // 262143

    float* out = (float*)d_out;
    hipMemsetAsync(d_out, 0, sizeof(float), stream);

    // --- workspace carve-up ---
    char* cur = (char*)d_ws;
    auto take = [&](size_t bytes) {
        char* p = cur;
        cur += (bytes + 255) & ~(size_t)255;
        return p;
    };
    ushort* featA = (ushort*)take((size_t)65536 * 256 * 2);
    ushort* featB = (ushort*)take((size_t)32768 * 256 * 2);
    ushort* Wz    = (ushort*)take((size_t)512 * 256 * 2);
    ushort* Wg    = (ushort*)take((size_t)1024 * 576 * 2);
    ushort* Wy    = (ushort*)take((size_t)320 * 128 * 2);
    float*  bg    = (float*) take((size_t)1024 * 4);
    ushort* Xb    = (ushort*)take((size_t)Nnodes * 8 * 2);
    const size_t fixed_used = (size_t)(cur - (char*)d_ws);
    // per-chunk: Zb 1024 + H 512 + C 512 = 2048 B/node
    int CB = 65536;
    while (CB > 2048 && fixed_used + (size_t)CB * 2048 + 4096 > ws_size) CB >>= 1;
    ushort* Zb = (ushort*)take((size_t)CB * 512 * 2);
    ushort* Hb = (ushort*)take((size_t)CB * 256 * 2);
    ushort* Cc = (ushort*)take((size_t)CB * 256 * 2);

    // --- one-time repack ---
    conv_f2b<<<(512 * 256 + 255) / 256, 256, 0, stream>>>(fc_h_W, Wz, 512 * 256);
    pack_wg<<<(1024 * 576 + 255) / 256, 256, 0, stream>>>(W_ih_d, W_hh_d, Wg);
    pack_bg<<<4, 256, 0, stream>>>(b_ih_d, b_hh_d, bg);
    pack_wy<<<(320 * 128 + 255) / 256, 256, 0, stream>>>(fc_W, Wy);
    conv_f2b<<<(Nnodes * 8 + 255) / 256, 256, 0, stream>>>(X, Xb, Nnodes * 8);

    encoder_root<<<1, 256, 0, stream>>>(X, Feature, W_ih_e, W_hh_e, b_ih_e, b_hh_e, featA);

    for (int l = 0; l < 17; ++l) {
        const int B = 1 << l;
        const long long nb = B - 1;
        ushort* Fcur  = (l & 1) ? featB : featA;
        ushort* Fnext = (l & 1) ? featA : featB;
        const int writeFeat = (l < 16) ? 1 : 0;
        const float scale = 1.f / ((float)B * 17.f);
        for (int j0 = 0; j0 < B; j0 += CB) {
            const int Bc = (B - j0 < CB) ? (B - j0) : CB;
            const int mg = (Bc + 127) / 128;
            // Z = tanh(Fcur @ Wz^T + fc_h_b): [Bc x 512] bf16
            gemm_bf16<1, 1><<<dim3(mg, 4), 256, 0, stream>>>(
                Fcur + (size_t)j0 * 256, 256, Bc - 1,
                Wz, 256, 511,
                fc_h_b, nullptr, nullptr, Zb, 512, Bc, 512, 256);
            // gates + LSTM fused -> H, C bf16
            gates_lstm<<<dim3(mg, 8), 256, 0, stream>>>(
                Xb + (size_t)(nb + j0) * 8,
                Fcur + (size_t)j0 * 256,
                Zb, Wg, bg, Hb, Cc, Bc);
            // Y-GEMM + NLL + swap + children (fused)
            ynll<<<(Bc + 15) / 16, 256, 0, stream>>>(
                Hb, Cc, Wy, fc_b, X,
                writeFeat ? Fnext : nullptr, out,
                Bc, nb, j0, scale, writeFeat);
        }
    }
}